// Round 1
// baseline (630.839 us; speedup 1.0000x reference)
//
#include <hip/hip_runtime.h>

#define N_NODES 12288
#define N_EDGES 393216
#define IN_FEAT 2000
#define HID 64

// ---------------- degrees ----------------
__global__ void deg_kernel(const int* __restrict__ src, const int* __restrict__ dst,
                           float* __restrict__ deg_out, float* __restrict__ deg_in) {
    int e = blockIdx.x * blockDim.x + threadIdx.x;
    if (e < N_EDGES) {
        atomicAdd(&deg_out[src[e]], 1.0f);
        atomicAdd(&deg_in[dst[e]], 1.0f);
    }
}

// deg -> deg^-0.5 (clipped at 1), in place over both arrays (2N contiguous)
__global__ void norm_kernel(float* __restrict__ deg) {
    int i = blockIdx.x * blockDim.x + threadIdx.x;
    if (i < 2 * N_NODES) {
        float d = fmaxf(deg[i], 1.0f);
        deg[i] = 1.0f / sqrtf(d);
    }
}

// ---------------- GEMM1: h += (A * out_norm[row]) @ W1, K split over blockIdx.y ----------------
__global__ __launch_bounds__(256) void gemm1_kernel(const float* __restrict__ A,
                                                    const float* __restrict__ W,
                                                    const float* __restrict__ out_norm,
                                                    float* __restrict__ h) {
    const int BK = 40;
    __shared__ __align__(16) float At[BK][68];   // [k][row]
    __shared__ __align__(16) float Ws[BK][68];   // [k][col]
    int t = threadIdx.x;
    int row0 = blockIdx.x * 64;
    int k0base = blockIdx.y * 1000;              // 2 * 1000 = 2000
    int tr = t >> 4, tc = t & 15;
    float acc[4][4] = {};

    for (int tile = 0; tile < 25; ++tile) {
        int k0 = k0base + tile * BK;
        __syncthreads();
#pragma unroll
        for (int i = 0; i < 10; ++i) {           // 64 rows x 40 k = 2560 elems
            int li = t + i * 256;
            int r = li / BK, kk = li % BK;
            float v = A[(size_t)(row0 + r) * IN_FEAT + (k0 + kk)] * out_norm[row0 + r];
            At[kk][r] = v;
        }
#pragma unroll
        for (int i = 0; i < 10; ++i) {           // 40 k x 64 cols
            int li = t + i * 256;
            int kk = li >> 6, c = li & 63;
            Ws[kk][c] = W[(k0 + kk) * HID + c];
        }
        __syncthreads();
#pragma unroll
        for (int kk = 0; kk < BK; ++kk) {
            float4 a4 = *(const float4*)&At[kk][tr * 4];
            float4 b4 = *(const float4*)&Ws[kk][tc * 4];
            float av[4] = {a4.x, a4.y, a4.z, a4.w};
            float bv[4] = {b4.x, b4.y, b4.z, b4.w};
#pragma unroll
            for (int m = 0; m < 4; ++m)
#pragma unroll
                for (int n = 0; n < 4; ++n)
                    acc[m][n] += av[m] * bv[n];
        }
    }
#pragma unroll
    for (int m = 0; m < 4; ++m)
#pragma unroll
        for (int n = 0; n < 4; ++n)
            atomicAdd(&h[(row0 + tr * 4 + m) * HID + tc * 4 + n], acc[m][n]);
}

// ---------------- scatter: agg[dst] += h[src] * ew, one wave per edge ----------------
__global__ __launch_bounds__(256) void scatter_kernel(const float* __restrict__ h,
                                                      const int* __restrict__ src,
                                                      const int* __restrict__ dst,
                                                      const float* __restrict__ ew,
                                                      float* __restrict__ agg) {
    int e = blockIdx.x * 4 + (threadIdx.x >> 6);
    int f = threadIdx.x & 63;
    if (e < N_EDGES) {
        int s = src[e], d = dst[e];
        float w = ew[e];
        atomicAdd(&agg[d * HID + f], h[s * HID + f] * w);
    }
}

// x1s = (agg * in_norm + b1) * out_norm   (layer-1 output pre-scaled for layer 2)
__global__ void e1_kernel(const float* __restrict__ agg, const float* __restrict__ in_norm,
                          const float* __restrict__ out_norm, const float* __restrict__ b1,
                          float* __restrict__ x1s) {
    int g = blockIdx.x * blockDim.x + threadIdx.x;
    if (g < N_NODES * HID) {
        int i = g >> 6, f = g & 63;
        x1s[g] = (agg[g] * in_norm[i] + b1[f]) * out_norm[i];
    }
}

// ---------------- GEMM2: h = x1s @ W2 (K=64) ----------------
__global__ __launch_bounds__(256) void gemm2_kernel(const float* __restrict__ x1s,
                                                    const float* __restrict__ W2,
                                                    float* __restrict__ h) {
    __shared__ float Ws[64][68];
    int t = threadIdx.x;
#pragma unroll
    for (int i = 0; i < 16; ++i) {
        int li = t + i * 256;
        Ws[li >> 6][li & 63] = W2[li];
    }
    __syncthreads();
    int row = blockIdx.x * 4 + (t >> 6);
    int c = t & 63;
    float acc = 0.f;
    const float4* xr = (const float4*)&x1s[row * HID];
#pragma unroll
    for (int k4 = 0; k4 < 16; ++k4) {
        float4 a = xr[k4];
        acc += a.x * Ws[k4 * 4 + 0][c];
        acc += a.y * Ws[k4 * 4 + 1][c];
        acc += a.z * Ws[k4 * 4 + 2][c];
        acc += a.w * Ws[k4 * 4 + 3][c];
    }
    h[row * HID + c] = acc;
}

// x = agg * in_norm + b2  -> written to d_out tail
__global__ void e2_kernel(const float* __restrict__ agg, const float* __restrict__ in_norm,
                          const float* __restrict__ b2, float* __restrict__ x) {
    int g = blockIdx.x * blockDim.x + threadIdx.x;
    if (g < N_NODES * HID) {
        int i = g >> 6, f = g & 63;
        x[g] = agg[g] * in_norm[i] + b2[f];
    }
}

// ---------------- decoder: adj = x @ x^T, 64x64 tile per block ----------------
__global__ __launch_bounds__(256) void adj_kernel(const float* __restrict__ x,
                                                  float* __restrict__ adj) {
    __shared__ __align__(16) float Xi[64][68];   // [k][i]
    __shared__ __align__(16) float Xj[64][68];   // [k][j]
    int t = threadIdx.x;
    int i0 = blockIdx.x * 64, j0 = blockIdx.y * 64;
#pragma unroll
    for (int i = 0; i < 4; ++i) {
        int fi = t + i * 256;          // 1024 float4s per 64x64 tile
        int r = fi >> 4, c4 = fi & 15;
        float4 v = *(const float4*)&x[(i0 + r) * HID + c4 * 4];
        Xi[c4 * 4 + 0][r] = v.x; Xi[c4 * 4 + 1][r] = v.y;
        Xi[c4 * 4 + 2][r] = v.z; Xi[c4 * 4 + 3][r] = v.w;
        float4 u = *(const float4*)&x[(j0 + r) * HID + c4 * 4];
        Xj[c4 * 4 + 0][r] = u.x; Xj[c4 * 4 + 1][r] = u.y;
        Xj[c4 * 4 + 2][r] = u.z; Xj[c4 * 4 + 3][r] = u.w;
    }
    __syncthreads();
    int tr = t >> 4, tc = t & 15;
    float acc[4][4] = {};
#pragma unroll 16
    for (int k = 0; k < 64; ++k) {
        float4 a4 = *(const float4*)&Xi[k][tr * 4];
        float4 b4 = *(const float4*)&Xj[k][tc * 4];
        float av[4] = {a4.x, a4.y, a4.z, a4.w};
        float bv[4] = {b4.x, b4.y, b4.z, b4.w};
#pragma unroll
        for (int m = 0; m < 4; ++m)
#pragma unroll
            for (int n = 0; n < 4; ++n)
                acc[m][n] += av[m] * bv[n];
    }
#pragma unroll
    for (int m = 0; m < 4; ++m) {
        float4 o = make_float4(acc[m][0], acc[m][1], acc[m][2], acc[m][3]);
        *(float4*)&adj[(size_t)(i0 + tr * 4 + m) * N_NODES + (j0 + tc * 4)] = o;
    }
}

extern "C" void kernel_launch(void* const* d_in, const int* in_sizes, int n_in,
                              void* d_out, int out_size, void* d_ws, size_t ws_size,
                              hipStream_t stream) {
    const float* features = (const float*)d_in[0];
    const float* ew       = (const float*)d_in[1];
    const float* W1       = (const float*)d_in[2];
    const float* b1       = (const float*)d_in[3];
    const float* W2       = (const float*)d_in[4];
    const float* b2       = (const float*)d_in[5];
    const int*   src      = (const int*)d_in[6];
    const int*   dst      = (const int*)d_in[7];

    float* out   = (float*)d_out;
    float* x_out = out + (size_t)N_NODES * N_NODES;   // second tuple element

    float* ws      = (float*)d_ws;
    float* deg_out = ws;                                // N   (becomes out_norm)
    float* deg_in  = ws + N_NODES;                      // N   (becomes in_norm)
    float* h       = ws + 2 * N_NODES;                  // N*HID
    float* agg     = h + N_NODES * HID;                 // N*HID
    float* x1s     = agg + N_NODES * HID;               // N*HID

    // zero deg (2N) + h (N*HID), contiguous
    hipMemsetAsync(ws, 0, (size_t)(2 * N_NODES + N_NODES * HID) * sizeof(float), stream);

    deg_kernel<<<N_EDGES / 256, 256, 0, stream>>>(src, dst, deg_out, deg_in);
    norm_kernel<<<(2 * N_NODES) / 256, 256, 0, stream>>>(ws);

    gemm1_kernel<<<dim3(N_NODES / 64, 2), 256, 0, stream>>>(features, W1, deg_out, h);

    hipMemsetAsync(agg, 0, (size_t)N_NODES * HID * sizeof(float), stream);
    scatter_kernel<<<N_EDGES / 4, 256, 0, stream>>>(h, src, dst, ew, agg);
    e1_kernel<<<N_NODES * HID / 256, 256, 0, stream>>>(agg, deg_in, deg_out, b1, x1s);

    gemm2_kernel<<<N_NODES / 4, 256, 0, stream>>>(x1s, W2, h);

    hipMemsetAsync(agg, 0, (size_t)N_NODES * HID * sizeof(float), stream);
    scatter_kernel<<<N_EDGES / 4, 256, 0, stream>>>(h, src, dst, ew, agg);
    e2_kernel<<<N_NODES * HID / 256, 256, 0, stream>>>(agg, deg_in, b2, x_out);

    adj_kernel<<<dim3(N_NODES / 64, N_NODES / 64), 256, 0, stream>>>(x_out, out);
}

// Round 2
// 499.634 us; speedup vs baseline: 1.2626x; 1.2626x over previous
//
#include <hip/hip_runtime.h>

#define N_NODES 12288
#define N_EDGES 393216
#define IN_FEAT 2000
#define HID 64

typedef __bf16 bf16x8 __attribute__((ext_vector_type(8)));
typedef float f32x16 __attribute__((ext_vector_type(16)));

// ---------------- degrees (float histograms) ----------------
__global__ void deg_kernel(const int* __restrict__ src, const int* __restrict__ dst,
                           float* __restrict__ deg_out, float* __restrict__ deg_in) {
    int e = blockIdx.x * blockDim.x + threadIdx.x;
    if (e < N_EDGES) {
        atomicAdd(&deg_out[src[e]], 1.0f);
        atomicAdd(&deg_in[dst[e]], 1.0f);
    }
}

// ---------------- CSR offsets: exclusive scan of deg_in (raw counts) ----------------
// single block, 256 threads, 48 contiguous elems each (256*48 = 12288)
__global__ __launch_bounds__(256) void scan_kernel(const float* __restrict__ deg_in,
                                                   int* __restrict__ offs,
                                                   int* __restrict__ cur) {
    __shared__ int sh[256];
    int t = threadIdx.x;
    int base = t * 48;
    int s = 0;
    for (int i = 0; i < 48; ++i) s += (int)deg_in[base + i];
    sh[t] = s;
    __syncthreads();
    // Hillis-Steele inclusive scan over 256 partials
    for (int off = 1; off < 256; off <<= 1) {
        int v = (t >= off) ? sh[t - off] : 0;
        __syncthreads();
        sh[t] += v;
        __syncthreads();
    }
    int run = sh[t] - s;   // exclusive prefix of this thread's chunk
    for (int i = 0; i < 48; ++i) {
        int c = (int)deg_in[base + i];
        offs[base + i] = run;
        cur[base + i] = run;
        run += c;
    }
    if (t == 255) offs[N_NODES] = run;
}

// deg -> clip(deg,1)^-0.5 in place over both arrays (2N contiguous)
__global__ void norm_kernel(float* __restrict__ deg) {
    int i = blockIdx.x * blockDim.x + threadIdx.x;
    if (i < 2 * N_NODES) {
        float d = fmaxf(deg[i], 1.0f);
        deg[i] = 1.0f / sqrtf(d);
    }
}

// ---------------- CSR bucket fill ----------------
__global__ void fill_kernel(const int* __restrict__ dst, int* __restrict__ cur,
                            int* __restrict__ eidx) {
    int e = blockIdx.x * blockDim.x + threadIdx.x;
    if (e < N_EDGES) {
        int p = atomicAdd(&cur[dst[e]], 1);
        eidx[p] = e;
    }
}

// ---------------- GEMM1: h += (A * out_norm[row]) @ W1, K split over blockIdx.y ----------------
__global__ __launch_bounds__(256) void gemm1_kernel(const float* __restrict__ A,
                                                    const float* __restrict__ W,
                                                    const float* __restrict__ out_norm,
                                                    float* __restrict__ h) {
    const int BK = 40;
    __shared__ __align__(16) float At[BK][68];   // [k][row]
    __shared__ __align__(16) float Ws[BK][68];   // [k][col]
    int t = threadIdx.x;
    int row0 = blockIdx.x * 64;
    int k0base = blockIdx.y * 1000;              // 2 * 1000 = 2000
    int tr = t >> 4, tc = t & 15;
    float acc[4][4] = {};

    for (int tile = 0; tile < 25; ++tile) {
        int k0 = k0base + tile * BK;
        __syncthreads();
#pragma unroll
        for (int i = 0; i < 10; ++i) {           // 64 rows x 40 k = 2560 elems
            int li = t + i * 256;
            int r = li / BK, kk = li % BK;
            float v = A[(size_t)(row0 + r) * IN_FEAT + (k0 + kk)] * out_norm[row0 + r];
            At[kk][r] = v;
        }
#pragma unroll
        for (int i = 0; i < 10; ++i) {           // 40 k x 64 cols
            int li = t + i * 256;
            int kk = li >> 6, c = li & 63;
            Ws[kk][c] = W[(k0 + kk) * HID + c];
        }
        __syncthreads();
#pragma unroll
        for (int kk = 0; kk < BK; ++kk) {
            float4 a4 = *(const float4*)&At[kk][tr * 4];
            float4 b4 = *(const float4*)&Ws[kk][tc * 4];
            float av[4] = {a4.x, a4.y, a4.z, a4.w};
            float bv[4] = {b4.x, b4.y, b4.z, b4.w};
#pragma unroll
            for (int m = 0; m < 4; ++m)
#pragma unroll
                for (int n = 0; n < 4; ++n)
                    acc[m][n] += av[m] * bv[n];
        }
    }
#pragma unroll
    for (int m = 0; m < 4; ++m)
#pragma unroll
        for (int n = 0; n < 4; ++n)
            atomicAdd(&h[(row0 + tr * 4 + m) * HID + tc * 4 + n], acc[m][n]);
}

// ---------------- gather layer 1 (fused epilogue): one wave per node, lane = feature ----------------
__global__ __launch_bounds__(256) void gather1_kernel(const float* __restrict__ h,
                                                      const int* __restrict__ src,
                                                      const float* __restrict__ ew,
                                                      const int* __restrict__ eidx,
                                                      const int* __restrict__ offs,
                                                      const float* __restrict__ in_norm,
                                                      const float* __restrict__ out_norm,
                                                      const float* __restrict__ b1,
                                                      float* __restrict__ x1s) {
    int n = blockIdx.x * 4 + (threadIdx.x >> 6);
    int f = threadIdx.x & 63;
    float acc = 0.f;
    int beg = offs[n], end = offs[n + 1];
    for (int p = beg; p < end; ++p) {
        int e = eidx[p];
        acc += h[src[e] * HID + f] * ew[e];
    }
    x1s[n * HID + f] = (acc * in_norm[n] + b1[f]) * out_norm[n];
}

// ---------------- GEMM2: h = x1s @ W2 (K=64) ----------------
__global__ __launch_bounds__(256) void gemm2_kernel(const float* __restrict__ x1s,
                                                    const float* __restrict__ W2,
                                                    float* __restrict__ h) {
    __shared__ float Ws[64][68];
    int t = threadIdx.x;
#pragma unroll
    for (int i = 0; i < 16; ++i) {
        int li = t + i * 256;
        Ws[li >> 6][li & 63] = W2[li];
    }
    __syncthreads();
    int row = blockIdx.x * 4 + (t >> 6);
    int c = t & 63;
    float acc = 0.f;
    const float4* xr = (const float4*)&x1s[row * HID];
#pragma unroll
    for (int k4 = 0; k4 < 16; ++k4) {
        float4 a = xr[k4];
        acc += a.x * Ws[k4 * 4 + 0][c];
        acc += a.y * Ws[k4 * 4 + 1][c];
        acc += a.z * Ws[k4 * 4 + 2][c];
        acc += a.w * Ws[k4 * 4 + 3][c];
    }
    h[row * HID + c] = acc;
}

// ---------------- gather layer 2 (fused epilogue + bf16 hi/lo split) ----------------
__global__ __launch_bounds__(256) void gather2_kernel(const float* __restrict__ h,
                                                      const int* __restrict__ src,
                                                      const float* __restrict__ ew,
                                                      const int* __restrict__ eidx,
                                                      const int* __restrict__ offs,
                                                      const float* __restrict__ in_norm,
                                                      const float* __restrict__ b2,
                                                      float* __restrict__ x_out,
                                                      __bf16* __restrict__ xh,
                                                      __bf16* __restrict__ xl) {
    int n = blockIdx.x * 4 + (threadIdx.x >> 6);
    int f = threadIdx.x & 63;
    float acc = 0.f;
    int beg = offs[n], end = offs[n + 1];
    for (int p = beg; p < end; ++p) {
        int e = eidx[p];
        acc += h[src[e] * HID + f] * ew[e];
    }
    float x = acc * in_norm[n] + b2[f];
    int g = n * HID + f;
    x_out[g] = x;
    __bf16 hb = (__bf16)x;
    xh[g] = hb;
    xl[g] = (__bf16)(x - (float)hb);
}

// ---------------- decoder: adj = x @ x^T via split-bf16 MFMA ----------------
// 128x128 tile per block, 4 waves, each wave: 32-row strip x 128 cols.
// mfma_f32_32x32x16_bf16. A frag: row = l&31, k = (l>>5)*8 + j.
// C/D: col = l&31, row = (r&3) + 8*(r>>2) + 4*(l>>5).
__global__ __launch_bounds__(256) void adj_kernel(const __bf16* __restrict__ xh,
                                                  const __bf16* __restrict__ xl,
                                                  float* __restrict__ adj) {
    int w = threadIdx.x >> 6, l = threadIdx.x & 63;
    int lr = l & 31, lh = l >> 5;
    int i0 = blockIdx.x * 128 + w * 32;
    int j0 = blockIdx.y * 128;

    // A fragments: 4 k-chunks of 16, hi and lo
    const __bf16* arow_h = xh + (size_t)(i0 + lr) * HID + lh * 8;
    const __bf16* arow_l = xl + (size_t)(i0 + lr) * HID + lh * 8;
    bf16x8 ah0 = *(const bf16x8*)(arow_h + 0);
    bf16x8 ah1 = *(const bf16x8*)(arow_h + 16);
    bf16x8 ah2 = *(const bf16x8*)(arow_h + 32);
    bf16x8 ah3 = *(const bf16x8*)(arow_h + 48);
    bf16x8 al0 = *(const bf16x8*)(arow_l + 0);
    bf16x8 al1 = *(const bf16x8*)(arow_l + 16);
    bf16x8 al2 = *(const bf16x8*)(arow_l + 32);
    bf16x8 al3 = *(const bf16x8*)(arow_l + 48);

#pragma unroll
    for (int ct = 0; ct < 4; ++ct) {
        const __bf16* brow_h = xh + (size_t)(j0 + ct * 32 + lr) * HID + lh * 8;
        const __bf16* brow_l = xl + (size_t)(j0 + ct * 32 + lr) * HID + lh * 8;
        bf16x8 bh0 = *(const bf16x8*)(brow_h + 0);
        bf16x8 bh1 = *(const bf16x8*)(brow_h + 16);
        bf16x8 bh2 = *(const bf16x8*)(brow_h + 32);
        bf16x8 bh3 = *(const bf16x8*)(brow_h + 48);
        bf16x8 bl0 = *(const bf16x8*)(brow_l + 0);
        bf16x8 bl1 = *(const bf16x8*)(brow_l + 16);
        bf16x8 bl2 = *(const bf16x8*)(brow_l + 32);
        bf16x8 bl3 = *(const bf16x8*)(brow_l + 48);

        f32x16 acc = {};
        acc = __builtin_amdgcn_mfma_f32_32x32x16_bf16(ah0, bh0, acc, 0, 0, 0);
        acc = __builtin_amdgcn_mfma_f32_32x32x16_bf16(ah1, bh1, acc, 0, 0, 0);
        acc = __builtin_amdgcn_mfma_f32_32x32x16_bf16(ah2, bh2, acc, 0, 0, 0);
        acc = __builtin_amdgcn_mfma_f32_32x32x16_bf16(ah3, bh3, acc, 0, 0, 0);
        acc = __builtin_amdgcn_mfma_f32_32x32x16_bf16(ah0, bl0, acc, 0, 0, 0);
        acc = __builtin_amdgcn_mfma_f32_32x32x16_bf16(ah1, bl1, acc, 0, 0, 0);
        acc = __builtin_amdgcn_mfma_f32_32x32x16_bf16(ah2, bl2, acc, 0, 0, 0);
        acc = __builtin_amdgcn_mfma_f32_32x32x16_bf16(ah3, bl3, acc, 0, 0, 0);
        acc = __builtin_amdgcn_mfma_f32_32x32x16_bf16(al0, bh0, acc, 0, 0, 0);
        acc = __builtin_amdgcn_mfma_f32_32x32x16_bf16(al1, bh1, acc, 0, 0, 0);
        acc = __builtin_amdgcn_mfma_f32_32x32x16_bf16(al2, bh2, acc, 0, 0, 0);
        acc = __builtin_amdgcn_mfma_f32_32x32x16_bf16(al3, bh3, acc, 0, 0, 0);

#pragma unroll
        for (int r = 0; r < 16; ++r) {
            int row = (r & 3) + 8 * (r >> 2) + 4 * lh;
            adj[(size_t)(i0 + row) * N_NODES + j0 + ct * 32 + lr] = acc[r];
        }
    }
}

extern "C" void kernel_launch(void* const* d_in, const int* in_sizes, int n_in,
                              void* d_out, int out_size, void* d_ws, size_t ws_size,
                              hipStream_t stream) {
    const float* features = (const float*)d_in[0];
    const float* ew       = (const float*)d_in[1];
    const float* W1       = (const float*)d_in[2];
    const float* b1       = (const float*)d_in[3];
    const float* W2       = (const float*)d_in[4];
    const float* b2       = (const float*)d_in[5];
    const int*   src      = (const int*)d_in[6];
    const int*   dst      = (const int*)d_in[7];

    float* out   = (float*)d_out;
    float* x_out = out + (size_t)N_NODES * N_NODES;   // second tuple element

    float* ws      = (float*)d_ws;
    float* deg_out = ws;                                // N   (becomes out_norm)
    float* deg_in  = ws + N_NODES;                      // N   (becomes in_norm)
    float* h       = ws + 2 * N_NODES;                  // N*HID
    float* x1s     = h + N_NODES * HID;                 // N*HID (later overlaid by xh/xl)
    int*   offs    = (int*)(x1s + N_NODES * HID);       // N+1
    int*   cur     = offs + N_NODES + 1;                // N
    int*   eidx    = cur + N_NODES;                     // E
    __bf16* xh     = (__bf16*)x1s;                      // N*HID bf16 (overlay, 16B aligned)
    __bf16* xl     = xh + N_NODES * HID;                // N*HID bf16

    // zero deg (2N) + h (N*HID), contiguous
    hipMemsetAsync(ws, 0, (size_t)(2 * N_NODES + N_NODES * HID) * sizeof(float), stream);

    deg_kernel<<<N_EDGES / 256, 256, 0, stream>>>(src, dst, deg_out, deg_in);
    scan_kernel<<<1, 256, 0, stream>>>(deg_in, offs, cur);     // raw counts -> offsets
    norm_kernel<<<(2 * N_NODES) / 256, 256, 0, stream>>>(ws);  // degs -> ^-0.5
    fill_kernel<<<N_EDGES / 256, 256, 0, stream>>>(dst, cur, eidx);

    gemm1_kernel<<<dim3(N_NODES / 64, 2), 256, 0, stream>>>(features, W1, deg_out, h);

    gather1_kernel<<<N_NODES / 4, 256, 0, stream>>>(h, src, ew, eidx, offs,
                                                    deg_in, deg_out, b1, x1s);

    gemm2_kernel<<<N_NODES / 4, 256, 0, stream>>>(x1s, W2, h);

    gather2_kernel<<<N_NODES / 4, 256, 0, stream>>>(h, src, ew, eidx, offs,
                                                    deg_in, b2, x_out, xh, xl);

    adj_kernel<<<dim3(N_NODES / 128, N_NODES / 128), 256, 0, stream>>>(xh, xl, out);
}

// Round 3
// 387.560 us; speedup vs baseline: 1.6277x; 1.2892x over previous
//
#include <hip/hip_runtime.h>

#define N_NODES 12288
#define N_EDGES 393216
#define IN_FEAT 2000
#define HID 64

typedef __bf16 bf16x8 __attribute__((ext_vector_type(8)));
typedef float f32x16 __attribute__((ext_vector_type(16)));

// ---------------- degrees (float histograms of raw counts) ----------------
__global__ void deg_kernel(const int* __restrict__ src, const int* __restrict__ dst,
                           float* __restrict__ deg_out, float* __restrict__ deg_in) {
    int e = blockIdx.x * blockDim.x + threadIdx.x;
    if (e < N_EDGES) {
        atomicAdd(&deg_out[src[e]], 1.0f);
        atomicAdd(&deg_in[dst[e]], 1.0f);
    }
}

// ---------------- CSR offsets: exclusive scan of deg_in (raw counts) ----------------
// single block, 256 threads, 48 contiguous elems each (256*48 = 12288)
__global__ __launch_bounds__(256) void scan_kernel(const float* __restrict__ deg_in,
                                                   int* __restrict__ offs,
                                                   int* __restrict__ cur) {
    __shared__ int sh[256];
    int t = threadIdx.x;
    int base = t * 48;
    int s = 0;
#pragma unroll
    for (int i = 0; i < 48; ++i) s += (int)deg_in[base + i];
    sh[t] = s;
    __syncthreads();
    for (int off = 1; off < 256; off <<= 1) {
        int v = (t >= off) ? sh[t - off] : 0;
        __syncthreads();
        sh[t] += v;
        __syncthreads();
    }
    int run = sh[t] - s;   // exclusive prefix of this thread's chunk
#pragma unroll
    for (int i = 0; i < 48; ++i) {
        int c = (int)deg_in[base + i];
        offs[base + i] = run;
        cur[base + i] = run;
        run += c;
    }
    if (t == 255) offs[N_NODES] = run;
}

// ---------------- CSR bucket fill: edata[p] = {src[e], bits(ew[e])} ----------------
__global__ void fill_kernel(const int* __restrict__ dst, const int* __restrict__ src,
                            const float* __restrict__ ew, int* __restrict__ cur,
                            int2* __restrict__ edata) {
    int e = blockIdx.x * blockDim.x + threadIdx.x;
    if (e < N_EDGES) {
        int p = atomicAdd(&cur[dst[e]], 1);
        edata[p] = make_int2(src[e], __float_as_int(ew[e]));
    }
}

// ---------------- GEMM1: h += (A * out_norm[row]) @ W1 via split-bf16 MFMA ----------------
// grid (192, 5): 64-row tiles x 5 K-splits (400 each). 4 waves: (w&1)=row half, (w>>1)=col half.
// No LDS, no barriers. A-frag: lane row = l&31, k = (l>>5)*8+j. B-frag: col = l&31, same k.
// C/D: col = l&31, row = (r&3)+8*(r>>2)+4*(l>>5)  [verified m74/m101].
__global__ __launch_bounds__(256) void gemm1_kernel(const float* __restrict__ A,
                                                    const float* __restrict__ W,
                                                    const float* __restrict__ deg_out,
                                                    float* __restrict__ h) {
    int t = threadIdx.x;
    int w = t >> 6, l = t & 63, lr = l & 31, lh = l >> 5;
    int row = blockIdx.x * 64 + (w & 1) * 32 + lr;   // this lane's A row (fixed)
    int col = (w >> 1) * 32 + lr;                    // this lane's B col (fixed)
    int kbase = blockIdx.y * 400;
    float norm = 1.0f / sqrtf(fmaxf(deg_out[row], 1.0f));
    const float* arow = A + (size_t)row * IN_FEAT + kbase + lh * 8;

    f32x16 acc = {};
    for (int c = 0; c < 25; ++c) {
        int k = c * 16;
        float4 a01 = *(const float4*)(arow + k);
        float4 a23 = *(const float4*)(arow + k + 4);
        const float* wp = W + (size_t)(kbase + k + lh * 8) * HID + col;
        float wf[8];
#pragma unroll
        for (int j = 0; j < 8; ++j) wf[j] = wp[j * HID];

        float af[8] = {a01.x, a01.y, a01.z, a01.w, a23.x, a23.y, a23.z, a23.w};
        bf16x8 ah, al, wh, wl;
#pragma unroll
        for (int j = 0; j < 8; ++j) {
            float v = af[j] * norm;
            __bf16 hb = (__bf16)v;
            ah[j] = hb;
            al[j] = (__bf16)(v - (float)hb);
            __bf16 wb = (__bf16)wf[j];
            wh[j] = wb;
            wl[j] = (__bf16)(wf[j] - (float)wb);
        }
        acc = __builtin_amdgcn_mfma_f32_32x32x16_bf16(ah, wh, acc, 0, 0, 0);
        acc = __builtin_amdgcn_mfma_f32_32x32x16_bf16(ah, wl, acc, 0, 0, 0);
        acc = __builtin_amdgcn_mfma_f32_32x32x16_bf16(al, wh, acc, 0, 0, 0);
    }
#pragma unroll
    for (int r = 0; r < 16; ++r) {
        int orow = blockIdx.x * 64 + (w & 1) * 32 + (r & 3) + 8 * (r >> 2) + 4 * lh;
        atomicAdd(&h[orow * HID + (w >> 1) * 32 + lr], acc[r]);
    }
}

// ---------------- gather layer 1 (fused epilogue): one wave per node, lane = feature ----------------
__global__ __launch_bounds__(256) void gather1_kernel(const float* __restrict__ h,
                                                      const int2* __restrict__ edata,
                                                      const int* __restrict__ offs,
                                                      const float* __restrict__ deg_in,
                                                      const float* __restrict__ deg_out,
                                                      const float* __restrict__ b1,
                                                      float* __restrict__ x1s) {
    int n = blockIdx.x * 4 + (threadIdx.x >> 6);
    int f = threadIdx.x & 63;
    float acc = 0.f;
    int beg = offs[n], end = offs[n + 1];
    int p = beg;
    for (; p + 4 <= end; p += 4) {
        int2 e0 = edata[p];
        int2 e1 = edata[p + 1];
        int2 e2 = edata[p + 2];
        int2 e3 = edata[p + 3];
        float h0 = h[(size_t)e0.x * HID + f];
        float h1 = h[(size_t)e1.x * HID + f];
        float h2 = h[(size_t)e2.x * HID + f];
        float h3 = h[(size_t)e3.x * HID + f];
        acc = fmaf(h0, __int_as_float(e0.y), acc);
        acc = fmaf(h1, __int_as_float(e1.y), acc);
        acc = fmaf(h2, __int_as_float(e2.y), acc);
        acc = fmaf(h3, __int_as_float(e3.y), acc);
    }
    for (; p < end; ++p) {
        int2 e = edata[p];
        acc = fmaf(h[(size_t)e.x * HID + f], __int_as_float(e.y), acc);
    }
    float in_norm = 1.0f / sqrtf(fmaxf(deg_in[n], 1.0f));
    float out_norm = 1.0f / sqrtf(fmaxf(deg_out[n], 1.0f));
    x1s[n * HID + f] = (acc * in_norm + b1[f]) * out_norm;
}

// ---------------- GEMM2: h = x1s @ W2 (K=64) ----------------
__global__ __launch_bounds__(256) void gemm2_kernel(const float* __restrict__ x1s,
                                                    const float* __restrict__ W2,
                                                    float* __restrict__ h) {
    __shared__ float Ws[64][68];
    int t = threadIdx.x;
#pragma unroll
    for (int i = 0; i < 16; ++i) {
        int li = t + i * 256;
        Ws[li >> 6][li & 63] = W2[li];
    }
    __syncthreads();
    int row = blockIdx.x * 4 + (t >> 6);
    int c = t & 63;
    float acc = 0.f;
    const float4* xr = (const float4*)&x1s[row * HID];
#pragma unroll
    for (int k4 = 0; k4 < 16; ++k4) {
        float4 a = xr[k4];
        acc += a.x * Ws[k4 * 4 + 0][c];
        acc += a.y * Ws[k4 * 4 + 1][c];
        acc += a.z * Ws[k4 * 4 + 2][c];
        acc += a.w * Ws[k4 * 4 + 3][c];
    }
    h[row * HID + c] = acc;
}

// ---------------- gather layer 2 (fused epilogue + bf16 hi/lo split) ----------------
__global__ __launch_bounds__(256) void gather2_kernel(const float* __restrict__ h,
                                                      const int2* __restrict__ edata,
                                                      const int* __restrict__ offs,
                                                      const float* __restrict__ deg_in,
                                                      const float* __restrict__ b2,
                                                      float* __restrict__ x_out,
                                                      __bf16* __restrict__ xh,
                                                      __bf16* __restrict__ xl) {
    int n = blockIdx.x * 4 + (threadIdx.x >> 6);
    int f = threadIdx.x & 63;
    float acc = 0.f;
    int beg = offs[n], end = offs[n + 1];
    int p = beg;
    for (; p + 4 <= end; p += 4) {
        int2 e0 = edata[p];
        int2 e1 = edata[p + 1];
        int2 e2 = edata[p + 2];
        int2 e3 = edata[p + 3];
        float h0 = h[(size_t)e0.x * HID + f];
        float h1 = h[(size_t)e1.x * HID + f];
        float h2 = h[(size_t)e2.x * HID + f];
        float h3 = h[(size_t)e3.x * HID + f];
        acc = fmaf(h0, __int_as_float(e0.y), acc);
        acc = fmaf(h1, __int_as_float(e1.y), acc);
        acc = fmaf(h2, __int_as_float(e2.y), acc);
        acc = fmaf(h3, __int_as_float(e3.y), acc);
    }
    for (; p < end; ++p) {
        int2 e = edata[p];
        acc = fmaf(h[(size_t)e.x * HID + f], __int_as_float(e.y), acc);
    }
    float in_norm = 1.0f / sqrtf(fmaxf(deg_in[n], 1.0f));
    float x = acc * in_norm + b2[f];
    int g = n * HID + f;
    x_out[g] = x;
    __bf16 hb = (__bf16)x;
    xh[g] = hb;
    xl[g] = (__bf16)(x - (float)hb);
}

// ---------------- decoder: adj = x @ x^T via split-bf16 MFMA ----------------
__global__ __launch_bounds__(256) void adj_kernel(const __bf16* __restrict__ xh,
                                                  const __bf16* __restrict__ xl,
                                                  float* __restrict__ adj) {
    int w = threadIdx.x >> 6, l = threadIdx.x & 63;
    int lr = l & 31, lh = l >> 5;
    int i0 = blockIdx.x * 128 + w * 32;
    int j0 = blockIdx.y * 128;

    const __bf16* arow_h = xh + (size_t)(i0 + lr) * HID + lh * 8;
    const __bf16* arow_l = xl + (size_t)(i0 + lr) * HID + lh * 8;
    bf16x8 ah0 = *(const bf16x8*)(arow_h + 0);
    bf16x8 ah1 = *(const bf16x8*)(arow_h + 16);
    bf16x8 ah2 = *(const bf16x8*)(arow_h + 32);
    bf16x8 ah3 = *(const bf16x8*)(arow_h + 48);
    bf16x8 al0 = *(const bf16x8*)(arow_l + 0);
    bf16x8 al1 = *(const bf16x8*)(arow_l + 16);
    bf16x8 al2 = *(const bf16x8*)(arow_l + 32);
    bf16x8 al3 = *(const bf16x8*)(arow_l + 48);

#pragma unroll
    for (int ct = 0; ct < 4; ++ct) {
        const __bf16* brow_h = xh + (size_t)(j0 + ct * 32 + lr) * HID + lh * 8;
        const __bf16* brow_l = xl + (size_t)(j0 + ct * 32 + lr) * HID + lh * 8;
        bf16x8 bh0 = *(const bf16x8*)(brow_h + 0);
        bf16x8 bh1 = *(const bf16x8*)(brow_h + 16);
        bf16x8 bh2 = *(const bf16x8*)(brow_h + 32);
        bf16x8 bh3 = *(const bf16x8*)(brow_h + 48);
        bf16x8 bl0 = *(const bf16x8*)(brow_l + 0);
        bf16x8 bl1 = *(const bf16x8*)(brow_l + 16);
        bf16x8 bl2 = *(const bf16x8*)(brow_l + 32);
        bf16x8 bl3 = *(const bf16x8*)(brow_l + 48);

        f32x16 acc = {};
        acc = __builtin_amdgcn_mfma_f32_32x32x16_bf16(ah0, bh0, acc, 0, 0, 0);
        acc = __builtin_amdgcn_mfma_f32_32x32x16_bf16(ah1, bh1, acc, 0, 0, 0);
        acc = __builtin_amdgcn_mfma_f32_32x32x16_bf16(ah2, bh2, acc, 0, 0, 0);
        acc = __builtin_amdgcn_mfma_f32_32x32x16_bf16(ah3, bh3, acc, 0, 0, 0);
        acc = __builtin_amdgcn_mfma_f32_32x32x16_bf16(ah0, bl0, acc, 0, 0, 0);
        acc = __builtin_amdgcn_mfma_f32_32x32x16_bf16(ah1, bl1, acc, 0, 0, 0);
        acc = __builtin_amdgcn_mfma_f32_32x32x16_bf16(ah2, bl2, acc, 0, 0, 0);
        acc = __builtin_amdgcn_mfma_f32_32x32x16_bf16(ah3, bl3, acc, 0, 0, 0);
        acc = __builtin_amdgcn_mfma_f32_32x32x16_bf16(al0, bh0, acc, 0, 0, 0);
        acc = __builtin_amdgcn_mfma_f32_32x32x16_bf16(al1, bh1, acc, 0, 0, 0);
        acc = __builtin_amdgcn_mfma_f32_32x32x16_bf16(al2, bh2, acc, 0, 0, 0);
        acc = __builtin_amdgcn_mfma_f32_32x32x16_bf16(al3, bh3, acc, 0, 0, 0);

#pragma unroll
        for (int r = 0; r < 16; ++r) {
            int row = (r & 3) + 8 * (r >> 2) + 4 * lh;
            adj[(size_t)(i0 + row) * N_NODES + j0 + ct * 32 + lr] = acc[r];
        }
    }
}

extern "C" void kernel_launch(void* const* d_in, const int* in_sizes, int n_in,
                              void* d_out, int out_size, void* d_ws, size_t ws_size,
                              hipStream_t stream) {
    const float* features = (const float*)d_in[0];
    const float* ew       = (const float*)d_in[1];
    const float* W1       = (const float*)d_in[2];
    const float* b1       = (const float*)d_in[3];
    const float* W2       = (const float*)d_in[4];
    const float* b2       = (const float*)d_in[5];
    const int*   src      = (const int*)d_in[6];
    const int*   dst      = (const int*)d_in[7];

    float* out   = (float*)d_out;
    float* x_out = out + (size_t)N_NODES * N_NODES;   // second tuple element

    float* ws      = (float*)d_ws;
    float* deg_out = ws;                                // N (raw counts)
    float* deg_in  = ws + N_NODES;                      // N (raw counts)
    float* h       = ws + 2 * N_NODES;                  // N*HID
    float* x1s     = h + N_NODES * HID;                 // N*HID (later overlaid by xh/xl)
    int*   offs    = (int*)(x1s + N_NODES * HID);       // N+1
    int*   cur     = offs + N_NODES + 1;                // N
    int2*  edata   = (int2*)(cur + N_NODES + 1);        // E int2 (8B aligned: offset even)
    __bf16* xh     = (__bf16*)x1s;                      // N*HID bf16 (overlay)
    __bf16* xl     = xh + N_NODES * HID;                // N*HID bf16

    // zero deg (2N) + h (N*HID), contiguous
    hipMemsetAsync(ws, 0, (size_t)(2 * N_NODES + N_NODES * HID) * sizeof(float), stream);

    deg_kernel<<<N_EDGES / 256, 256, 0, stream>>>(src, dst, deg_out, deg_in);
    scan_kernel<<<1, 256, 0, stream>>>(deg_in, offs, cur);
    fill_kernel<<<N_EDGES / 256, 256, 0, stream>>>(dst, src, ew, cur, edata);

    gemm1_kernel<<<dim3(N_NODES / 64, 5), 256, 0, stream>>>(features, W1, deg_out, h);

    gather1_kernel<<<N_NODES / 4, 256, 0, stream>>>(h, edata, offs, deg_in, deg_out, b1, x1s);

    gemm2_kernel<<<N_NODES / 4, 256, 0, stream>>>(x1s, W2, h);

    gather2_kernel<<<N_NODES / 4, 256, 0, stream>>>(h, edata, offs, deg_in, b2, x_out, xh, xl);

    adj_kernel<<<dim3(N_NODES / 128, N_NODES / 128), 256, 0, stream>>>(xh, xl, out);
}

// Round 4
// 306.826 us; speedup vs baseline: 2.0560x; 1.2631x over previous
//
#include <hip/hip_runtime.h>

#define N_NODES 12288
#define N_EDGES 393216
#define IN_FEAT 2000
#define HID 64

typedef __bf16 bf16x8 __attribute__((ext_vector_type(8)));
typedef float f32x16 __attribute__((ext_vector_type(16)));

// ---------------- degrees (float histograms of raw counts) ----------------
__global__ void deg_kernel(const int* __restrict__ src, const int* __restrict__ dst,
                           float* __restrict__ deg_out, float* __restrict__ deg_in) {
    int e = blockIdx.x * blockDim.x + threadIdx.x;
    if (e < N_EDGES) {
        atomicAdd(&deg_out[src[e]], 1.0f);
        atomicAdd(&deg_in[dst[e]], 1.0f);
    }
}

// ---------------- CSR offsets: exclusive scan of deg_in (raw counts) ----------------
// single block, 1024 threads, 12 contiguous elems each (1024*12 = 12288)
__global__ __launch_bounds__(1024) void scan_kernel(const float* __restrict__ deg_in,
                                                    int* __restrict__ offs,
                                                    int* __restrict__ cur) {
    __shared__ int sh[1024];
    int t = threadIdx.x;
    int base = t * 12;
    int s = 0;
#pragma unroll
    for (int i = 0; i < 12; ++i) s += (int)deg_in[base + i];
    sh[t] = s;
    __syncthreads();
    for (int off = 1; off < 1024; off <<= 1) {
        int v = (t >= off) ? sh[t - off] : 0;
        __syncthreads();
        sh[t] += v;
        __syncthreads();
    }
    int run = sh[t] - s;   // exclusive prefix of this thread's chunk
#pragma unroll
    for (int i = 0; i < 12; ++i) {
        int c = (int)deg_in[base + i];
        offs[base + i] = run;
        cur[base + i] = run;
        run += c;
    }
    if (t == 1023) offs[N_NODES] = run;
}

// ---------------- CSR bucket fill: edata[p] = {src[e], bits(ew[e])} ----------------
__global__ void fill_kernel(const int* __restrict__ dst, const int* __restrict__ src,
                            const float* __restrict__ ew, int* __restrict__ cur,
                            int2* __restrict__ edata) {
    int e = blockIdx.x * blockDim.x + threadIdx.x;
    if (e < N_EDGES) {
        int p = atomicAdd(&cur[dst[e]], 1);
        edata[p] = make_int2(src[e], __float_as_int(ew[e]));
    }
}

// ---------------- GEMM1: h += (A * out_norm[row]) @ W1 via split-bf16 MFMA ----------------
__global__ __launch_bounds__(256) void gemm1_kernel(const float* __restrict__ A,
                                                    const float* __restrict__ W,
                                                    const float* __restrict__ deg_out,
                                                    float* __restrict__ h) {
    int t = threadIdx.x;
    int w = t >> 6, l = t & 63, lr = l & 31, lh = l >> 5;
    int row = blockIdx.x * 64 + (w & 1) * 32 + lr;   // this lane's A row (fixed)
    int col = (w >> 1) * 32 + lr;                    // this lane's B col (fixed)
    int kbase = blockIdx.y * 400;
    float norm = 1.0f / sqrtf(fmaxf(deg_out[row], 1.0f));
    const float* arow = A + (size_t)row * IN_FEAT + kbase + lh * 8;

    f32x16 acc = {};
    for (int c = 0; c < 25; ++c) {
        int k = c * 16;
        float4 a01 = *(const float4*)(arow + k);
        float4 a23 = *(const float4*)(arow + k + 4);
        const float* wp = W + (size_t)(kbase + k + lh * 8) * HID + col;
        float wf[8];
#pragma unroll
        for (int j = 0; j < 8; ++j) wf[j] = wp[j * HID];

        float af[8] = {a01.x, a01.y, a01.z, a01.w, a23.x, a23.y, a23.z, a23.w};
        bf16x8 ah, al, wh, wl;
#pragma unroll
        for (int j = 0; j < 8; ++j) {
            float v = af[j] * norm;
            __bf16 hb = (__bf16)v;
            ah[j] = hb;
            al[j] = (__bf16)(v - (float)hb);
            __bf16 wb = (__bf16)wf[j];
            wh[j] = wb;
            wl[j] = (__bf16)(wf[j] - (float)wb);
        }
        acc = __builtin_amdgcn_mfma_f32_32x32x16_bf16(ah, wh, acc, 0, 0, 0);
        acc = __builtin_amdgcn_mfma_f32_32x32x16_bf16(ah, wl, acc, 0, 0, 0);
        acc = __builtin_amdgcn_mfma_f32_32x32x16_bf16(al, wh, acc, 0, 0, 0);
    }
#pragma unroll
    for (int r = 0; r < 16; ++r) {
        int orow = blockIdx.x * 64 + (w & 1) * 32 + (r & 3) + 8 * (r >> 2) + 4 * lh;
        atomicAdd(&h[orow * HID + (w >> 1) * 32 + lr], acc[r]);
    }
}

// ---------------- gather layer 1 (fused epilogue): one wave per node, lane = feature ----------------
__global__ __launch_bounds__(256) void gather1_kernel(const float* __restrict__ h,
                                                      const int2* __restrict__ edata,
                                                      const int* __restrict__ offs,
                                                      const float* __restrict__ deg_in,
                                                      const float* __restrict__ deg_out,
                                                      const float* __restrict__ b1,
                                                      float* __restrict__ x1s) {
    int n = blockIdx.x * 4 + (threadIdx.x >> 6);
    int f = threadIdx.x & 63;
    float acc = 0.f;
    int beg = offs[n], end = offs[n + 1];
    int p = beg;
    for (; p + 4 <= end; p += 4) {
        int2 e0 = edata[p];
        int2 e1 = edata[p + 1];
        int2 e2 = edata[p + 2];
        int2 e3 = edata[p + 3];
        float h0 = h[(size_t)e0.x * HID + f];
        float h1 = h[(size_t)e1.x * HID + f];
        float h2 = h[(size_t)e2.x * HID + f];
        float h3 = h[(size_t)e3.x * HID + f];
        acc = fmaf(h0, __int_as_float(e0.y), acc);
        acc = fmaf(h1, __int_as_float(e1.y), acc);
        acc = fmaf(h2, __int_as_float(e2.y), acc);
        acc = fmaf(h3, __int_as_float(e3.y), acc);
    }
    for (; p < end; ++p) {
        int2 e = edata[p];
        acc = fmaf(h[(size_t)e.x * HID + f], __int_as_float(e.y), acc);
    }
    float in_norm = 1.0f / sqrtf(fmaxf(deg_in[n], 1.0f));
    float out_norm = 1.0f / sqrtf(fmaxf(deg_out[n], 1.0f));
    x1s[n * HID + f] = (acc * in_norm + b1[f]) * out_norm;
}

// ---------------- GEMM2: h = x1s @ W2 (K=64) ----------------
__global__ __launch_bounds__(256) void gemm2_kernel(const float* __restrict__ x1s,
                                                    const float* __restrict__ W2,
                                                    float* __restrict__ h) {
    __shared__ float Ws[64][68];
    int t = threadIdx.x;
#pragma unroll
    for (int i = 0; i < 16; ++i) {
        int li = t + i * 256;
        Ws[li >> 6][li & 63] = W2[li];
    }
    __syncthreads();
    int row = blockIdx.x * 4 + (t >> 6);
    int c = t & 63;
    float acc = 0.f;
    const float4* xr = (const float4*)&x1s[row * HID];
#pragma unroll
    for (int k4 = 0; k4 < 16; ++k4) {
        float4 a = xr[k4];
        acc += a.x * Ws[k4 * 4 + 0][c];
        acc += a.y * Ws[k4 * 4 + 1][c];
        acc += a.z * Ws[k4 * 4 + 2][c];
        acc += a.w * Ws[k4 * 4 + 3][c];
    }
    h[row * HID + c] = acc;
}

// ---------------- gather layer 2 (fused epilogue + bf16 hi/lo split) ----------------
__global__ __launch_bounds__(256) void gather2_kernel(const float* __restrict__ h,
                                                      const int2* __restrict__ edata,
                                                      const int* __restrict__ offs,
                                                      const float* __restrict__ deg_in,
                                                      const float* __restrict__ b2,
                                                      float* __restrict__ x_out,
                                                      __bf16* __restrict__ xh,
                                                      __bf16* __restrict__ xl) {
    int n = blockIdx.x * 4 + (threadIdx.x >> 6);
    int f = threadIdx.x & 63;
    float acc = 0.f;
    int beg = offs[n], end = offs[n + 1];
    int p = beg;
    for (; p + 4 <= end; p += 4) {
        int2 e0 = edata[p];
        int2 e1 = edata[p + 1];
        int2 e2 = edata[p + 2];
        int2 e3 = edata[p + 3];
        float h0 = h[(size_t)e0.x * HID + f];
        float h1 = h[(size_t)e1.x * HID + f];
        float h2 = h[(size_t)e2.x * HID + f];
        float h3 = h[(size_t)e3.x * HID + f];
        acc = fmaf(h0, __int_as_float(e0.y), acc);
        acc = fmaf(h1, __int_as_float(e1.y), acc);
        acc = fmaf(h2, __int_as_float(e2.y), acc);
        acc = fmaf(h3, __int_as_float(e3.y), acc);
    }
    for (; p < end; ++p) {
        int2 e = edata[p];
        acc = fmaf(h[(size_t)e.x * HID + f], __int_as_float(e.y), acc);
    }
    float in_norm = 1.0f / sqrtf(fmaxf(deg_in[n], 1.0f));
    float x = acc * in_norm + b2[f];
    int g = n * HID + f;
    x_out[g] = x;
    __bf16 hb = (__bf16)x;
    xh[g] = hb;
    xl[g] = (__bf16)(x - (float)hb);
}

// ---------------- decoder: adj = x @ x^T via split-bf16 MFMA ----------------
// 128x128 tile/block, 4 waves. j-panel (B operand, 128 rows x 64 cols, hi+lo)
// staged in LDS with XOR-swizzled 16B chunks (chunk ^= row&7) -> conflict-free
// ds_read_b128 for the stride-128B fragment reads; panel shared by all 4 waves.
// A fragments per-wave in registers. Nontemporal stores (604 MB stream).
__global__ __launch_bounds__(256) void adj_kernel(const __bf16* __restrict__ xh,
                                                  const __bf16* __restrict__ xl,
                                                  float* __restrict__ adj) {
    __shared__ __align__(16) char Bh[16384];   // 128 rows x 128 B
    __shared__ __align__(16) char Bl[16384];
    int t = threadIdx.x;
    int w = t >> 6, l = t & 63;
    int lr = l & 31, lh = l >> 5;
    int i0 = blockIdx.x * 128 + w * 32;
    int j0 = blockIdx.y * 128;

    // stage j-panel: 1024 16B-chunks per array, coalesced global read, swizzled LDS write
    const char* gh = (const char*)(xh + (size_t)j0 * HID);
    const char* gl = (const char*)(xl + (size_t)j0 * HID);
#pragma unroll
    for (int i = 0; i < 4; ++i) {
        int c = t + i * 256;               // chunk id 0..1023
        int row = c >> 3, cin = c & 7;
        int dst = row * 128 + ((cin ^ (row & 7)) << 4);
        *(float4*)(Bh + dst) = *(const float4*)(gh + c * 16);
        *(float4*)(Bl + dst) = *(const float4*)(gl + c * 16);
    }

    // A fragments (this wave's 32 rows), issued before the barrier to overlap
    const __bf16* arow_h = xh + (size_t)(i0 + lr) * HID + lh * 8;
    const __bf16* arow_l = xl + (size_t)(i0 + lr) * HID + lh * 8;
    bf16x8 ah[4], al[4];
#pragma unroll
    for (int kc = 0; kc < 4; ++kc) {
        ah[kc] = *(const bf16x8*)(arow_h + kc * 16);
        al[kc] = *(const bf16x8*)(arow_l + kc * 16);
    }
    __syncthreads();

#pragma unroll
    for (int ct = 0; ct < 4; ++ct) {
        int row = ct * 32 + lr;
        int rbase = row * 128, rx = row & 7;
        bf16x8 bh[4], bl[4];
#pragma unroll
        for (int kc = 0; kc < 4; ++kc) {
            int off = rbase + (((kc * 2 + lh) ^ rx) << 4);
            bh[kc] = *(const bf16x8*)(Bh + off);
            bl[kc] = *(const bf16x8*)(Bl + off);
        }
        f32x16 acc = {};
        acc = __builtin_amdgcn_mfma_f32_32x32x16_bf16(ah[0], bh[0], acc, 0, 0, 0);
        acc = __builtin_amdgcn_mfma_f32_32x32x16_bf16(ah[1], bh[1], acc, 0, 0, 0);
        acc = __builtin_amdgcn_mfma_f32_32x32x16_bf16(ah[2], bh[2], acc, 0, 0, 0);
        acc = __builtin_amdgcn_mfma_f32_32x32x16_bf16(ah[3], bh[3], acc, 0, 0, 0);
        acc = __builtin_amdgcn_mfma_f32_32x32x16_bf16(ah[0], bl[0], acc, 0, 0, 0);
        acc = __builtin_amdgcn_mfma_f32_32x32x16_bf16(ah[1], bl[1], acc, 0, 0, 0);
        acc = __builtin_amdgcn_mfma_f32_32x32x16_bf16(ah[2], bl[2], acc, 0, 0, 0);
        acc = __builtin_amdgcn_mfma_f32_32x32x16_bf16(ah[3], bl[3], acc, 0, 0, 0);
        acc = __builtin_amdgcn_mfma_f32_32x32x16_bf16(al[0], bh[0], acc, 0, 0, 0);
        acc = __builtin_amdgcn_mfma_f32_32x32x16_bf16(al[1], bh[1], acc, 0, 0, 0);
        acc = __builtin_amdgcn_mfma_f32_32x32x16_bf16(al[2], bh[2], acc, 0, 0, 0);
        acc = __builtin_amdgcn_mfma_f32_32x32x16_bf16(al[3], bh[3], acc, 0, 0, 0);

#pragma unroll
        for (int r = 0; r < 16; ++r) {
            int rrow = (r & 3) + 8 * (r >> 2) + 4 * lh;
            __builtin_nontemporal_store(acc[r],
                &adj[(size_t)(i0 + rrow) * N_NODES + j0 + ct * 32 + lr]);
        }
    }
}

extern "C" void kernel_launch(void* const* d_in, const int* in_sizes, int n_in,
                              void* d_out, int out_size, void* d_ws, size_t ws_size,
                              hipStream_t stream) {
    const float* features = (const float*)d_in[0];
    const float* ew       = (const float*)d_in[1];
    const float* W1       = (const float*)d_in[2];
    const float* b1       = (const float*)d_in[3];
    const float* W2       = (const float*)d_in[4];
    const float* b2       = (const float*)d_in[5];
    const int*   src      = (const int*)d_in[6];
    const int*   dst      = (const int*)d_in[7];

    float* out   = (float*)d_out;
    float* x_out = out + (size_t)N_NODES * N_NODES;   // second tuple element

    float* ws      = (float*)d_ws;
    float* deg_out = ws;                                // N (raw counts)
    float* deg_in  = ws + N_NODES;                      // N (raw counts)
    float* h       = ws + 2 * N_NODES;                  // N*HID
    float* x1s     = h + N_NODES * HID;                 // N*HID (later overlaid by xh/xl)
    int*   offs    = (int*)(x1s + N_NODES * HID);       // N+1
    int*   cur     = offs + N_NODES + 1;                // N
    int2*  edata   = (int2*)(cur + N_NODES + 1);        // E int2 (8B aligned)
    __bf16* xh     = (__bf16*)x1s;                      // N*HID bf16 (overlay)
    __bf16* xl     = xh + N_NODES * HID;                // N*HID bf16

    // zero deg (2N) + h (N*HID), contiguous
    hipMemsetAsync(ws, 0, (size_t)(2 * N_NODES + N_NODES * HID) * sizeof(float), stream);

    deg_kernel<<<N_EDGES / 256, 256, 0, stream>>>(src, dst, deg_out, deg_in);
    scan_kernel<<<1, 1024, 0, stream>>>(deg_in, offs, cur);
    fill_kernel<<<N_EDGES / 256, 256, 0, stream>>>(dst, src, ew, cur, edata);

    gemm1_kernel<<<dim3(N_NODES / 64, 5), 256, 0, stream>>>(features, W1, deg_out, h);

    gather1_kernel<<<N_NODES / 4, 256, 0, stream>>>(h, edata, offs, deg_in, deg_out, b1, x1s);

    gemm2_kernel<<<N_NODES / 4, 256, 0, stream>>>(x1s, W2, h);

    gather2_kernel<<<N_NODES / 4, 256, 0, stream>>>(h, edata, offs, deg_in, b2, x_out, xh, xl);

    adj_kernel<<<dim3(N_NODES / 128, N_NODES / 128), 256, 0, stream>>>(xh, xl, out);
}